// Round 2
// baseline (2688.244 us; speedup 1.0000x reference)
//
#include <hip/hip_runtime.h>

// ============================================================================
// SEB_59201829208446: conv1x1 -> BN(train stats)+ReLU -> covpool ->
//   out = sqrtm(cov); E = expm(-cov); att = out@E; nrm = ||att||_F;
//   y = out*(1+nrm); upper-triangle output.
// sqrtm via Newton-Schulz (18 it, Frobenius-normalized).
// expm via scaling-squaring: Taylor-8 on -cov/32, then 5 squarings -> e^{-cov}.
// Round 2: fixed-role buffers + explicit copies (no pointer swapping),
// literal att GEMM + Frobenius reduction (no trace identity).
// ============================================================================

namespace {
constexpr long MSZ = 65536; // 256*256

// ---- tiled GEMM body: C = alpha*(A@B) + diag*I.  64x64 tile, 4x4 micro, BK=16
// A [M x K] row-major, B [K x N] row-major. Rows assumed in-bounds (M%64==0);
// N bound-checked when NB. K % 16 == 0.
template<bool NB>
__device__ __forceinline__
void mm_body(const float* __restrict__ A, const float* __restrict__ Bm,
             float* __restrict__ C, int Ndim, int Kdim, float alpha, float diag)
{
  __shared__ float As[16][64];
  __shared__ float Bs[16][64];
  const int tid = threadIdx.x;
  const int tx = tid & 15, ty = tid >> 4;
  const int row0 = blockIdx.y * 64, col0 = blockIdx.x * 64;
  const int ar = tid >> 2, ac = (tid & 3) * 4;   // A-tile: 64 rows x 16 k
  const int br = tid >> 4, bc = (tid & 15) * 4;  // B-tile: 16 k x 64 cols
  float acc[4][4] = {};

  for (int k0 = 0; k0 < Kdim; k0 += 16) {
    const float4 av = *reinterpret_cast<const float4*>(A + (long)(row0 + ar) * Kdim + k0 + ac);
    As[ac + 0][ar] = av.x; As[ac + 1][ar] = av.y;
    As[ac + 2][ar] = av.z; As[ac + 3][ar] = av.w;
    float4 bv = make_float4(0.f, 0.f, 0.f, 0.f);
    if (!NB || (col0 + bc) < Ndim)
      bv = *reinterpret_cast<const float4*>(Bm + (long)(k0 + br) * Ndim + col0 + bc);
    *reinterpret_cast<float4*>(&Bs[br][bc]) = bv;
    __syncthreads();
#pragma unroll
    for (int kk = 0; kk < 16; ++kk) {
      const float4 a4 = *reinterpret_cast<const float4*>(&As[kk][ty * 4]);
      const float4 b4 = *reinterpret_cast<const float4*>(&Bs[kk][tx * 4]);
      const float aa[4] = {a4.x, a4.y, a4.z, a4.w};
      const float bb[4] = {b4.x, b4.y, b4.z, b4.w};
#pragma unroll
      for (int i = 0; i < 4; ++i)
#pragma unroll
        for (int j = 0; j < 4; ++j)
          acc[i][j] = fmaf(aa[i], bb[j], acc[i][j]);
    }
    __syncthreads();
  }
#pragma unroll
  for (int i = 0; i < 4; ++i) {
    const int r = row0 + ty * 4 + i;
#pragma unroll
    for (int j = 0; j < 4; ++j) {
      const int c = col0 + tx * 4 + j;
      if (NB && c >= Ndim) continue;
      float v = alpha * acc[i][j];
      if (r == c) v += diag;
      C[(long)r * Ndim + c] = v;
    }
  }
}
} // namespace

template<bool NB>
__global__ __launch_bounds__(256)
void gemm_k(const float* __restrict__ A, const float* __restrict__ Bm,
            float* __restrict__ C, int Ndim, int Kdim,
            long sA, long sB, long sC, float alpha, float diag)
{
  const int bz = blockIdx.z;
  mm_body<NB>(A + (long)bz * sA, Bm + (long)bz * sB, C + (long)bz * sC,
              Ndim, Kdim, alpha, diag);
}

// plain batched copy: grid (256, 32), block 256
__global__ __launch_bounds__(256)
void copy_k(const float* __restrict__ src, float* __restrict__ dst)
{
  const long i = (long)blockIdx.y * MSZ + (long)blockIdx.x * 256 + threadIdx.x;
  dst[i] = src[i];
}

// ---- BN batch statistics over (b, m) for each channel d -------------------
__global__ __launch_bounds__(256)
void bn_stats_k(const float* __restrict__ z, float* __restrict__ sum, float* __restrict__ sumsq)
{
  const int d = blockIdx.x;
  float s = 0.f, q = 0.f;
  for (int b = 0; b < 32; ++b) {
    const float* p = z + ((long)b * 256 + d) * 784;
    for (int m = threadIdx.x; m < 784; m += 256) {
      const float v = p[m];
      s += v; q = fmaf(v, v, q);
    }
  }
  __shared__ float ws[4], wq[4];
  const int lane = threadIdx.x & 63, wid = threadIdx.x >> 6;
#pragma unroll
  for (int o = 32; o > 0; o >>= 1) { s += __shfl_down(s, o); q += __shfl_down(q, o); }
  if (lane == 0) { ws[wid] = s; wq[wid] = q; }
  __syncthreads();
  if (threadIdx.x == 0) {
    sum[d]   = ws[0] + ws[1] + ws[2] + ws[3];
    sumsq[d] = wq[0] + wq[1] + wq[2] + wq[3];
  }
}

__global__ void bn_params_k(const float* __restrict__ sum, const float* __restrict__ sumsq,
                            const float* __restrict__ gamma, const float* __restrict__ beta,
                            float* __restrict__ scale, float* __restrict__ shift)
{
  const int d = threadIdx.x;
  const float inv_n = 1.f / 25088.f;
  const float mean = sum[d] * inv_n;
  const float var  = sumsq[d] * inv_n - mean * mean;
  const float sc = gamma[d] / sqrtf(var + 1e-5f);
  scale[d] = sc;
  shift[d] = fmaf(-mean, sc, beta[d]);
}

// per-(b,d) spatial sum of BN+ReLU'd z (for covariance mean subtraction)
__global__ __launch_bounds__(64)
void rowsum_k(const float* __restrict__ z, const float* __restrict__ scale,
              const float* __restrict__ shift, float* __restrict__ rs)
{
  const int d = blockIdx.x, b = blockIdx.y;
  const float sc = scale[d], sh = shift[d];
  const float* p = z + ((long)b * 256 + d) * 784;
  float s = 0.f;
  for (int m = threadIdx.x; m < 784; m += 64)
    s += fmaxf(fmaf(p[m], sc, sh), 0.f);
#pragma unroll
  for (int o = 32; o > 0; o >>= 1) s += __shfl_down(s, o);
  if (threadIdx.x == 0) rs[b * 256 + d] = s;
}

// cov[b] = (Zt Zt^T)/784 - mu mu^T, BN+ReLU applied on the fly while loading z
__global__ __launch_bounds__(256)
void gram_cov_k(const float* __restrict__ z, const float* __restrict__ scale,
                const float* __restrict__ shift, const float* __restrict__ rs,
                float* __restrict__ cov)
{
  __shared__ float As[16][64];
  __shared__ float Bs[16][64];
  const int tid = threadIdx.x;
  const int tx = tid & 15, ty = tid >> 4;
  const int e0 = blockIdx.x * 64, d0 = blockIdx.y * 64, b = blockIdx.z;
  const float* zb = z + (long)b * 256 * 784;
  const int lr = tid >> 2, lc = (tid & 3) * 4;
  const float scA = scale[d0 + lr], shA = shift[d0 + lr];
  const float scB = scale[e0 + lr], shB = shift[e0 + lr];
  float acc[4][4] = {};
  for (int m0 = 0; m0 < 784; m0 += 16) {   // 784 = 49*16 exact
    const float4 a = *reinterpret_cast<const float4*>(zb + (long)(d0 + lr) * 784 + m0 + lc);
    As[lc + 0][lr] = fmaxf(fmaf(a.x, scA, shA), 0.f);
    As[lc + 1][lr] = fmaxf(fmaf(a.y, scA, shA), 0.f);
    As[lc + 2][lr] = fmaxf(fmaf(a.z, scA, shA), 0.f);
    As[lc + 3][lr] = fmaxf(fmaf(a.w, scA, shA), 0.f);
    const float4 c4 = *reinterpret_cast<const float4*>(zb + (long)(e0 + lr) * 784 + m0 + lc);
    Bs[lc + 0][lr] = fmaxf(fmaf(c4.x, scB, shB), 0.f);
    Bs[lc + 1][lr] = fmaxf(fmaf(c4.y, scB, shB), 0.f);
    Bs[lc + 2][lr] = fmaxf(fmaf(c4.z, scB, shB), 0.f);
    Bs[lc + 3][lr] = fmaxf(fmaf(c4.w, scB, shB), 0.f);
    __syncthreads();
#pragma unroll
    for (int kk = 0; kk < 16; ++kk) {
      const float4 a4 = *reinterpret_cast<const float4*>(&As[kk][ty * 4]);
      const float4 b4 = *reinterpret_cast<const float4*>(&Bs[kk][tx * 4]);
      const float aa[4] = {a4.x, a4.y, a4.z, a4.w};
      const float bb[4] = {b4.x, b4.y, b4.z, b4.w};
#pragma unroll
      for (int i = 0; i < 4; ++i)
#pragma unroll
        for (int j = 0; j < 4; ++j)
          acc[i][j] = fmaf(aa[i], bb[j], acc[i][j]);
    }
    __syncthreads();
  }
  const float inv_m = 1.f / 784.f;
#pragma unroll
  for (int i = 0; i < 4; ++i) {
    const int d = d0 + ty * 4 + i;
    const float mu_d = rs[b * 256 + d] * inv_m;
#pragma unroll
    for (int j = 0; j < 4; ++j) {
      const int e = e0 + tx * 4 + j;
      const float mu_e = rs[b * 256 + e] * inv_m;
      cov[((long)b * 256 + d) * 256 + e] = fmaf(acc[i][j], inv_m, -mu_d * mu_e);
    }
  }
}

// Frobenius norm per batch matrix (also reused for ||att||/sqrt(cfro))
__global__ __launch_bounds__(256)
void frob_k(const float* __restrict__ M, float* __restrict__ outv)
{
  const int b = blockIdx.x;
  const float* p = M + (long)b * MSZ;
  float s = 0.f;
  for (int i = threadIdx.x; i < 65536; i += 256) { const float v = p[i]; s = fmaf(v, v, s); }
  __shared__ float ws[4];
  const int lane = threadIdx.x & 63, wid = threadIdx.x >> 6;
#pragma unroll
  for (int o = 32; o > 0; o >>= 1) s += __shfl_down(s, o);
  if (lane == 0) ws[wid] = s;
  __syncthreads();
  if (threadIdx.x == 0) outv[b] = sqrtf(ws[0] + ws[1] + ws[2] + ws[3]);
}

__global__ __launch_bounds__(256)
void ns_init_k(const float* __restrict__ cov, const float* __restrict__ cfro,
               float* __restrict__ Y, float* __restrict__ Z)
{
  const int b = blockIdx.y;
  const int idx = blockIdx.x * 256 + threadIdx.x;
  const long o = (long)b * MSZ + idx;
  const float inv = 1.f / cfro[b];
  Y[o] = cov[o] * inv;
  Z[o] = ((idx >> 8) == (idx & 255)) ? 1.f : 0.f;
}

// X = -cov/32 ; E0 = X/8! + I/7!  (first Horner step folded in)
__global__ __launch_bounds__(256)
void expm_init_k(const float* __restrict__ cov, float* __restrict__ X,
                 float* __restrict__ E)
{
  const int b = blockIdx.y;
  const int idx = blockIdx.x * 256 + threadIdx.x;
  const long o = (long)b * MSZ + idx;
  const float x = cov[o] * (-1.f / 32.f);
  X[o] = x;
  float v = x * (1.f / 40320.f);
  if ((idx >> 8) == (idx & 255)) v += 1.f / 5040.f;
  E[o] = v;
}

// y = sqrt(cfro)*Y*(1+nrm), nrm = sqrt(cfro)*||Y@E||_F; upper-triangle extract
__global__ __launch_bounds__(256)
void out_k(const float* __restrict__ Y, const float* __restrict__ cfro,
           const float* __restrict__ attn, float* __restrict__ out)
{
  const int i = blockIdx.x, b = blockIdx.y, j = threadIdx.x;
  if (j < i) return;
  const float sc = sqrtf(cfro[b]);
  const float nrm = fmaxf(sc * attn[b], 1e-12f);
  const float s = sc * (1.f + nrm);
  const long off = (long)b * 32896 + (long)i * 256 - (long)i * (i - 1) / 2 + (j - i);
  out[off] = Y[((long)b * 256 + i) * 256 + j] * s;
}

extern "C" void kernel_launch(void* const* d_in, const int* in_sizes, int n_in,
                              void* d_out, int out_size, void* d_ws, size_t ws_size,
                              hipStream_t stream)
{
  const float* x     = (const float*)d_in[0];   // [32,2048,28,28]
  const float* w     = (const float*)d_in[1];   // [256,2048]
  const float* gamma = (const float*)d_in[2];
  const float* beta  = (const float*)d_in[3];
  float* out = (float*)d_out;
  float* ws  = (float*)d_ws;

  // Fixed-role workspace layout (floats). z spans [0, 6422528) and is DEAD
  // after gram_cov; Y/Z/T live in that region (3 x 2097152 = 6291456 fits).
  // Total footprint ~50.9 MB (same as round 1 — no new OOB risk).
  float* z   = ws;
  float* Y   = ws;               // sqrtm iterate (post-gram only)
  float* Zb  = ws + 2097152;     // NS Z iterate
  float* T   = ws + 4194304;     // NS T / expm X
  float* cov = ws + 6422528;
  float* S   = ws + 8519680;     // universal GEMM scratch
  float* E   = ws + 10616832;    // expm iterate
  float* st  = ws + 12713984;
  float* sum = st, *sumsq = st + 256, *scale = st + 512, *shift = st + 768;
  float* rs   = st + 1024;       // 32*256
  float* cfro = st + 9216;
  float* attn = st + 9248;

  const dim3 blk(256);
  const dim3 gM(4, 4, 32);       // 256x256 batched GEMM grid
  const dim3 gC(256, 32);        // batched elementwise grid

  // 1) z[b] = W @ X_b    (256x784x2048 per batch item)
  gemm_k<true><<<dim3(13, 4, 32), blk, 0, stream>>>(
      w, x, z, 784, 2048, 0L, (long)2048 * 784, (long)256 * 784, 1.f, 0.f);
  // 2) BN batch stats + affine params
  bn_stats_k<<<dim3(256), blk, 0, stream>>>(z, sum, sumsq);
  bn_params_k<<<dim3(1), blk, 0, stream>>>(sum, sumsq, gamma, beta, scale, shift);
  // 3) per-(b,d) spatial sums of BN+ReLU output
  rowsum_k<<<dim3(256, 32), dim3(64), 0, stream>>>(z, scale, shift, rs);
  // 4) covariance
  gram_cov_k<<<gM, blk, 0, stream>>>(z, scale, shift, rs, cov);
  // 5) per-batch Frobenius norm; NS init (Y = cov/cfro, Z = I)
  frob_k<<<dim3(32), blk, 0, stream>>>(cov, cfro);
  ns_init_k<<<gC, blk, 0, stream>>>(cov, cfro, Y, Zb);

  // 6) Newton-Schulz (18 it): T = 1.5I - 0.5*Z@Y ; Y <- Y@T ; Z <- T@Z
  //    Fixed buffers, explicit copies — no pointer rotation.
  for (int it = 0; it < 18; ++it) {
    gemm_k<false><<<gM, blk, 0, stream>>>(Zb, Y, T, 256, 256, MSZ, MSZ, MSZ, -0.5f, 1.5f);
    gemm_k<false><<<gM, blk, 0, stream>>>(Y, T, S, 256, 256, MSZ, MSZ, MSZ, 1.f, 0.f);
    copy_k<<<gC, blk, 0, stream>>>(S, Y);
    gemm_k<false><<<gM, blk, 0, stream>>>(T, Zb, S, 256, 256, MSZ, MSZ, MSZ, 1.f, 0.f);
    copy_k<<<gC, blk, 0, stream>>>(S, Zb);
  }
  // Y = sqrtm(cov)/sqrt(cfro)

  // 7) E = expm(-cov): X = -cov/32 (in T); Taylor-8 Horner (7 GEMMs);
  //    5 squarings -> (e^X)^32 = e^{-cov}
  expm_init_k<<<gC, blk, 0, stream>>>(cov, T, E);
  const float cjs[7] = {1.f/720.f, 1.f/120.f, 1.f/24.f, 1.f/6.f, 0.5f, 1.f, 1.f};
  for (int h = 0; h < 7; ++h) {
    gemm_k<false><<<gM, blk, 0, stream>>>(T, E, S, 256, 256, MSZ, MSZ, MSZ, 1.f, cjs[h]);
    copy_k<<<gC, blk, 0, stream>>>(S, E);
  }
  for (int q = 0; q < 5; ++q) {
    gemm_k<false><<<gM, blk, 0, stream>>>(E, E, S, 256, 256, MSZ, MSZ, MSZ, 1.f, 0.f);
    copy_k<<<gC, blk, 0, stream>>>(S, E);
  }

  // 8) att/sqrt(cfro) = Y@E ; nrm = sqrt(cfro)*||Y@E||_F ; epilogue
  gemm_k<false><<<gM, blk, 0, stream>>>(Y, E, S, 256, 256, MSZ, MSZ, MSZ, 1.f, 0.f);
  frob_k<<<dim3(32), blk, 0, stream>>>(S, attn);
  out_k<<<gC, blk, 0, stream>>>(Y, cfro, attn, out);
}

// Round 3
// 1063.486 us; speedup vs baseline: 2.5278x; 2.5278x over previous
//
#include <hip/hip_runtime.h>

// ============================================================================
// SEB_59201829208446 round 3: MFMA everywhere.
//   conv1x1 (bf16 MFMA) -> BN(batch stats)+ReLU -> covpool (bf16 MFMA Gram)
//   -> An = cov/(1.1*lambda_max) via power iteration
//   -> Z-only Newton-Schulz (9 it, split-bf16 MFMA):  Z -> An^{-1/2}
//   -> S1 = An@Z = An^{1/2};  out = S1/sqrt(s)
//   -> E = expm(-cov) via Paterson-Stockmeyer deg-8 on X=-cov/2, then square
//   -> S2 = S1@E; nrm = ||S2||_F/sqrt(s); y = out*(1+nrm), upper-tri.
// Split-bf16: M = Mh + Ml (two bf16 planes); C = AhBh+AhBl+AlBh, fp32 accum.
// ============================================================================

typedef unsigned short u16;
typedef __attribute__((ext_vector_type(8))) short bf16x8;
typedef __attribute__((ext_vector_type(4))) float f32x4;

__device__ __forceinline__ u16 f2bf(float f) {
  unsigned u = __builtin_bit_cast(unsigned, f);
  u += 0x7FFFu + ((u >> 16) & 1u);
  return (u16)(u >> 16);
}
__device__ __forceinline__ float bf2f(u16 h) {
  unsigned u = ((unsigned)h) << 16;
  return __builtin_bit_cast(float, u);
}

// ---------------------------------------------------------------------------
// Batched 256x256x256 split-bf16 GEMM.  C = alpha*(A@B) [+ b1*P] [+ diag*I].
// REQUIRES B symmetric (B-operand fragments are read as rows of B == B^T rows).
// Tiles 128x128, BK=64, 4 waves (2x2), 16x16x32 bf16 MFMA.
// LDS chunk layout: chunk(m, c) = 8 bf16 of row m, k-chunk c, stored at
// lds[t][m][c ^ (m&7)] (XOR swizzle -> 2-way-free bank pattern).
// ---------------------------------------------------------------------------
template<bool HASP>
__global__ __launch_bounds__(256)
void gemm2_k(const u16* __restrict__ Ah, const u16* __restrict__ Al,
             const u16* __restrict__ Bh, const u16* __restrict__ Bl,
             u16* __restrict__ Ch, u16* __restrict__ Cl,
             const u16* __restrict__ Ph, const u16* __restrict__ Pl,
             float alpha, float b1, float diag)
{
  __shared__ u16 lds[4][128][8][8];   // Ah, Al, Bh, Bl tiles: 64 KB
  const int tid = threadIdx.x;
  const long boff = (long)blockIdx.z * 65536;
  const int row0 = blockIdx.y * 128, col0 = blockIdx.x * 128;
  const int wave = tid >> 6, lane = tid & 63;
  const int wm = wave >> 1, wn = wave & 1;
  const int mL = lane & 15, q = lane >> 4;
  const u16* baseA[2] = {Ah + boff, Al + boff};
  const u16* baseB[2] = {Bh + boff, Bl + boff};

  f32x4 acc[4][4];
#pragma unroll
  for (int i = 0; i < 4; ++i)
#pragma unroll
    for (int j = 0; j < 4; ++j) acc[i][j] = {0.f, 0.f, 0.f, 0.f};

  for (int k0 = 0; k0 < 256; k0 += 64) {
    __syncthreads();
#pragma unroll
    for (int it = 0; it < 16; ++it) {
      const int t = it >> 2;                    // 0:Ah 1:Al 2:Bh 3:Bl
      const int r = ((it & 3) << 8) + tid;      // 0..1023 within tile
      const int m = r >> 3, c = r & 7;
      const u16* src = (t < 2 ? baseA[t] : baseB[t - 2])
                     + (long)((t < 2 ? row0 : col0) + m) * 256 + k0 + c * 8;
      const uint4 v = *reinterpret_cast<const uint4*>(src);
      *reinterpret_cast<uint4*>(&lds[t][m][c ^ (m & 7)][0]) = v;
    }
    __syncthreads();
#pragma unroll
    for (int kk = 0; kk < 2; ++kk) {
      bf16x8 ah[4], al[4], bh[4], bl[4];
#pragma unroll
      for (int i = 0; i < 4; ++i) {
        const int ma = wm * 64 + i * 16 + mL;
        const int ca = (kk * 4 + q) ^ (ma & 7);
        ah[i] = *reinterpret_cast<const bf16x8*>(&lds[0][ma][ca][0]);
        al[i] = *reinterpret_cast<const bf16x8*>(&lds[1][ma][ca][0]);
        const int nb = wn * 64 + i * 16 + mL;
        const int cb = (kk * 4 + q) ^ (nb & 7);
        bh[i] = *reinterpret_cast<const bf16x8*>(&lds[2][nb][cb][0]);
        bl[i] = *reinterpret_cast<const bf16x8*>(&lds[3][nb][cb][0]);
      }
#pragma unroll
      for (int i = 0; i < 4; ++i)
#pragma unroll
        for (int j = 0; j < 4; ++j) {
          acc[i][j] = __builtin_amdgcn_mfma_f32_16x16x32_bf16(ah[i], bh[j], acc[i][j], 0, 0, 0);
          acc[i][j] = __builtin_amdgcn_mfma_f32_16x16x32_bf16(ah[i], bl[j], acc[i][j], 0, 0, 0);
          acc[i][j] = __builtin_amdgcn_mfma_f32_16x16x32_bf16(al[i], bh[j], acc[i][j], 0, 0, 0);
        }
    }
  }
  // epilogue: C/D layout col=lane&15, row=quad*4+reg
#pragma unroll
  for (int i = 0; i < 4; ++i) {
    const int rbase = row0 + wm * 64 + i * 16 + q * 4;
#pragma unroll
    for (int j = 0; j < 4; ++j) {
      const int cc = col0 + wn * 64 + j * 16 + mL;
#pragma unroll
      for (int rg = 0; rg < 4; ++rg) {
        const int rr = rbase + rg;
        const long o = boff + (long)rr * 256 + cc;
        float v = alpha * acc[i][j][rg];
        if (HASP) v = fmaf(b1, bf2f(Ph[o]) + bf2f(Pl[o]), v);
        if (rr == cc) v += diag;
        const u16 h = f2bf(v);
        Ch[o] = h;
        Cl[o] = f2bf(v - bf2f(h));
      }
    }
  }
}

// ---------------------------------------------------------------------------
// conv1x1: z[b] = W(256x2048) @ x_b(2048x784), bf16 MFMA, fp32 out.
// Tile M=256 (full), N=128, BK=64, 8 waves (4x2). x is transposed during
// staging (global rows are k-major; B-operand wants [n][k]).
// ---------------------------------------------------------------------------
__global__ __launch_bounds__(512)
void conv_k(const u16* __restrict__ wb, const float* __restrict__ x,
            float* __restrict__ z)
{
  __shared__ u16 ldsA[256][8][8];   // 32 KB
  __shared__ u16 ldsB[128][8][8];   // 16 KB
  const int tid = threadIdx.x;
  const int b = blockIdx.z;
  const int n0 = blockIdx.x * 128;
  const int wave = tid >> 6, lane = tid & 63;
  const int wm = wave >> 1, wn = wave & 1;   // 4 x 2 waves of 64x64
  const int mL = lane & 15, q = lane >> 4;
  const float* xb = x + (long)b * 2048 * 784;

  f32x4 acc[4][4];
#pragma unroll
  for (int i = 0; i < 4; ++i)
#pragma unroll
    for (int j = 0; j < 4; ++j) acc[i][j] = {0.f, 0.f, 0.f, 0.f};

  for (int k0 = 0; k0 < 2048; k0 += 64) {
    __syncthreads();
    // stage A (wb rows): 2048 chunks / 512 thr = 4 each
#pragma unroll
    for (int it = 0; it < 4; ++it) {
      const int g = it * 512 + tid;
      const int m = g >> 3, c = g & 7;
      const uint4 v = *reinterpret_cast<const uint4*>(wb + (long)m * 2048 + k0 + c * 8);
      *reinterpret_cast<uint4*>(&ldsA[m][c ^ (m & 7)][0]) = v;
    }
    // stage B with transpose + fp32->bf16: thread = (kg 0..15, nc 0..31)
    {
      const int kg = tid >> 5, nc = tid & 31;
      const int kbase = kg * 4, nbase = nc * 4;
      float vv[4][4];
#pragma unroll
      for (int jk = 0; jk < 4; ++jk) {
        const int gk = k0 + kbase + jk;
        const int gn = n0 + nbase;
        float4 f = make_float4(0.f, 0.f, 0.f, 0.f);
        if (gn < 784) f = *reinterpret_cast<const float4*>(xb + (long)gk * 784 + gn);
        vv[jk][0] = f.x; vv[jk][1] = f.y; vv[jk][2] = f.z; vv[jk][3] = f.w;
      }
      const int c = kbase >> 3, ko = kbase & 7;
#pragma unroll
      for (int jn = 0; jn < 4; ++jn) {
        const int n = nbase + jn;
        ushort4 u;
        u.x = f2bf(vv[0][jn]); u.y = f2bf(vv[1][jn]);
        u.z = f2bf(vv[2][jn]); u.w = f2bf(vv[3][jn]);
        *reinterpret_cast<ushort4*>(&ldsB[n][c ^ (n & 7)][ko]) = u;
      }
    }
    __syncthreads();
#pragma unroll
    for (int kk = 0; kk < 2; ++kk) {
      bf16x8 af[4], bfv[4];
#pragma unroll
      for (int i = 0; i < 4; ++i) {
        const int ma = wm * 64 + i * 16 + mL;
        af[i] = *reinterpret_cast<const bf16x8*>(&ldsA[ma][(kk * 4 + q) ^ (ma & 7)][0]);
        const int nb = wn * 64 + i * 16 + mL;
        bfv[i] = *reinterpret_cast<const bf16x8*>(&ldsB[nb][(kk * 4 + q) ^ (nb & 7)][0]);
      }
#pragma unroll
      for (int i = 0; i < 4; ++i)
#pragma unroll
        for (int j = 0; j < 4; ++j)
          acc[i][j] = __builtin_amdgcn_mfma_f32_16x16x32_bf16(af[i], bfv[j], acc[i][j], 0, 0, 0);
    }
  }
#pragma unroll
  for (int i = 0; i < 4; ++i) {
    const int rbase = wm * 64 + i * 16 + q * 4;
#pragma unroll
    for (int j = 0; j < 4; ++j) {
      const int cc = n0 + wn * 64 + j * 16 + mL;
      if (cc >= 784) continue;
#pragma unroll
      for (int rg = 0; rg < 4; ++rg)
        z[((long)b * 256 + rbase + rg) * 784 + cc] = acc[i][j][rg];
    }
  }
}

// ---------------------------------------------------------------------------
// Gram: cov[b] = (1/784) zb@zb^T - mu mu^T.  zb bf16 [256][832] (zero-padded).
// ---------------------------------------------------------------------------
__global__ __launch_bounds__(256)
void gram_k(const u16* __restrict__ zb, const float* __restrict__ rs,
            float* __restrict__ cov)
{
  __shared__ u16 lds[2][128][8][8];   // 32 KB
  const int tid = threadIdx.x;
  const int b = blockIdx.z;
  const int col0 = blockIdx.x * 128, row0 = blockIdx.y * 128;
  const int wave = tid >> 6, lane = tid & 63;
  const int wm = wave >> 1, wn = wave & 1;
  const int mL = lane & 15, q = lane >> 4;
  const u16* zbb = zb + (long)b * 256 * 832;

  f32x4 acc[4][4];
#pragma unroll
  for (int i = 0; i < 4; ++i)
#pragma unroll
    for (int j = 0; j < 4; ++j) acc[i][j] = {0.f, 0.f, 0.f, 0.f};

  for (int k0 = 0; k0 < 832; k0 += 64) {
    __syncthreads();
#pragma unroll
    for (int it = 0; it < 8; ++it) {
      const int t = it >> 2;
      const int r = ((it & 3) << 8) + tid;
      const int m = r >> 3, c = r & 7;
      const int grow = (t == 0 ? row0 : col0) + m;
      const uint4 v = *reinterpret_cast<const uint4*>(zbb + (long)grow * 832 + k0 + c * 8);
      *reinterpret_cast<uint4*>(&lds[t][m][c ^ (m & 7)][0]) = v;
    }
    __syncthreads();
#pragma unroll
    for (int kk = 0; kk < 2; ++kk) {
      bf16x8 af[4], bfv[4];
#pragma unroll
      for (int i = 0; i < 4; ++i) {
        const int ma = wm * 64 + i * 16 + mL;
        af[i] = *reinterpret_cast<const bf16x8*>(&lds[0][ma][(kk * 4 + q) ^ (ma & 7)][0]);
        const int nb = wn * 64 + i * 16 + mL;
        bfv[i] = *reinterpret_cast<const bf16x8*>(&lds[1][nb][(kk * 4 + q) ^ (nb & 7)][0]);
      }
#pragma unroll
      for (int i = 0; i < 4; ++i)
#pragma unroll
        for (int j = 0; j < 4; ++j)
          acc[i][j] = __builtin_amdgcn_mfma_f32_16x16x32_bf16(af[i], bfv[j], acc[i][j], 0, 0, 0);
    }
  }
  const float inv_m = 1.f / 784.f;
#pragma unroll
  for (int i = 0; i < 4; ++i) {
    const int rr0 = row0 + wm * 64 + i * 16 + q * 4;
#pragma unroll
    for (int j = 0; j < 4; ++j) {
      const int cc = col0 + wn * 64 + j * 16 + mL;
      const float mu_c = rs[b * 256 + cc] * inv_m;
#pragma unroll
      for (int rg = 0; rg < 4; ++rg) {
        const int rr = rr0 + rg;
        const float mu_r = rs[b * 256 + rr] * inv_m;
        cov[((long)b * 256 + rr) * 256 + cc] = fmaf(acc[i][j][rg], inv_m, -mu_r * mu_c);
      }
    }
  }
}

// ---- small kernels ---------------------------------------------------------
__global__ __launch_bounds__(256)
void cast_w_k(const float* __restrict__ w, u16* __restrict__ wb)
{
  const int idx = blockIdx.x * 256 + threadIdx.x;
  wb[idx] = f2bf(w[idx]);
}

__global__ __launch_bounds__(256)
void bn_stats_k(const float* __restrict__ z, float* __restrict__ sum, float* __restrict__ sumsq)
{
  const int d = blockIdx.x;
  float s = 0.f, qq = 0.f;
  for (int b = 0; b < 32; ++b) {
    const float* p = z + ((long)b * 256 + d) * 784;
    for (int m = threadIdx.x; m < 784; m += 256) {
      const float v = p[m];
      s += v; qq = fmaf(v, v, qq);
    }
  }
  __shared__ float ws[4], wq[4];
  const int lane = threadIdx.x & 63, wid = threadIdx.x >> 6;
#pragma unroll
  for (int o = 32; o > 0; o >>= 1) { s += __shfl_down(s, o); qq += __shfl_down(qq, o); }
  if (lane == 0) { ws[wid] = s; wq[wid] = qq; }
  __syncthreads();
  if (threadIdx.x == 0) {
    sum[d]   = ws[0] + ws[1] + ws[2] + ws[3];
    sumsq[d] = wq[0] + wq[1] + wq[2] + wq[3];
  }
}

__global__ void bn_params_k(const float* __restrict__ sum, const float* __restrict__ sumsq,
                            const float* __restrict__ gamma, const float* __restrict__ beta,
                            float* __restrict__ scale, float* __restrict__ shift)
{
  const int d = threadIdx.x;
  const float inv_n = 1.f / 25088.f;
  const float mean = sum[d] * inv_n;
  const float var  = sumsq[d] * inv_n - mean * mean;
  const float sc = gamma[d] / sqrtf(var + 1e-5f);
  scale[d] = sc;
  shift[d] = fmaf(-mean, sc, beta[d]);
}

__global__ __launch_bounds__(64)
void rowsum_k(const float* __restrict__ z, const float* __restrict__ scale,
              const float* __restrict__ shift, float* __restrict__ rs)
{
  const int d = blockIdx.x, b = blockIdx.y;
  const float sc = scale[d], sh = shift[d];
  const float* p = z + ((long)b * 256 + d) * 784;
  float s = 0.f;
  for (int m = threadIdx.x; m < 784; m += 64)
    s += fmaxf(fmaf(p[m], sc, sh), 0.f);
#pragma unroll
  for (int o = 32; o > 0; o >>= 1) s += __shfl_down(s, o);
  if (threadIdx.x == 0) rs[b * 256 + d] = s;
}

__global__ __launch_bounds__(256)
void bnrelu_cast_k(const float* __restrict__ z, const float* __restrict__ scale,
                   const float* __restrict__ shift, u16* __restrict__ zb)
{
  const int d = blockIdx.x, b = blockIdx.y;
  const float sc = scale[d], sh = shift[d];
  const float* p = z + ((long)b * 256 + d) * 784;
  u16* qp = zb + ((long)b * 256 + d) * 832;
  for (int m = threadIdx.x; m < 832; m += 256) {
    const float v = (m < 784) ? fmaxf(fmaf(p[m], sc, sh), 0.f) : 0.f;
    qp[m] = f2bf(v);
  }
}

__global__ __launch_bounds__(256)
void power_k(const float* __restrict__ cov, float* __restrict__ s)
{
  const int b = blockIdx.x;
  const float* A = cov + (long)b * 65536;
  __shared__ float v[256];
  __shared__ float red[4];
  const int i = threadIdx.x;
  v[i] = 1.f;
  __syncthreads();
  float lam = 1.f;
  for (int it = 0; it < 16; ++it) {
    const float* row = A + (long)i * 256;
    float u = 0.f;
#pragma unroll 8
    for (int j = 0; j < 256; ++j) u = fmaf(row[j], v[j], u);
    float ss = u * u;
#pragma unroll
    for (int o = 32; o > 0; o >>= 1) ss += __shfl_down(ss, o);
    if ((i & 63) == 0) red[i >> 6] = ss;
    __syncthreads();
    const float n2 = red[0] + red[1] + red[2] + red[3];
    lam = sqrtf(n2);
    v[i] = u / lam;
    __syncthreads();
  }
  if (i == 0) s[b] = 1.f / (1.10f * lam);
}

__global__ __launch_bounds__(256)
void init_ns_k(const float* __restrict__ cov, const float* __restrict__ s,
               u16* __restrict__ Anh, u16* __restrict__ Anl,
               u16* __restrict__ Z1h, u16* __restrict__ Z1l)
{
  const int b = blockIdx.y, i = blockIdx.x, j = threadIdx.x;
  const long o = ((long)b * 256 + i) * 256 + j;
  const float a = cov[o] * s[b];
  const u16 h = f2bf(a);
  Anh[o] = h; Anl[o] = f2bf(a - bf2f(h));
  Z1h[o] = (i == j) ? f2bf(1.f) : (u16)0;
  Z1l[o] = 0;
}

__global__ __launch_bounds__(256)
void x_init_k(const float* __restrict__ cov, u16* __restrict__ Xh, u16* __restrict__ Xl)
{
  const int b = blockIdx.y, i = blockIdx.x, j = threadIdx.x;
  const long o = ((long)b * 256 + i) * 256 + j;
  const float a = cov[o] * -0.5f;
  const u16 h = f2bf(a);
  Xh[o] = h; Xl[o] = f2bf(a - bf2f(h));
}

// H3 = I/720 + X/5040 + X2/40320
__global__ __launch_bounds__(256)
void h3_k(const u16* __restrict__ X2h, const u16* __restrict__ X2l,
          const u16* __restrict__ Xh, const u16* __restrict__ Xl,
          u16* __restrict__ Oh, u16* __restrict__ Ol)
{
  const int b = blockIdx.y, i = blockIdx.x, j = threadIdx.x;
  const long o = ((long)b * 256 + i) * 256 + j;
  float v = (bf2f(X2h[o]) + bf2f(X2l[o])) * (1.f / 40320.f)
          + (bf2f(Xh[o]) + bf2f(Xl[o])) * (1.f / 5040.f);
  if (i == j) v += 1.f / 720.f;
  const u16 h = f2bf(v);
  Oh[o] = h; Ol[o] = f2bf(v - bf2f(h));
}

__global__ __launch_bounds__(256)
void frob2_k(const u16* __restrict__ Mh, const u16* __restrict__ Ml, float* __restrict__ outv)
{
  const int b = blockIdx.x;
  const u16* ph = Mh + (long)b * 65536;
  const u16* pl = Ml + (long)b * 65536;
  float ss = 0.f;
  for (int i = threadIdx.x; i < 65536; i += 256) {
    const float v = bf2f(ph[i]) + bf2f(pl[i]);
    ss = fmaf(v, v, ss);
  }
  __shared__ float ws[4];
  const int lane = threadIdx.x & 63, wid = threadIdx.x >> 6;
#pragma unroll
  for (int o = 32; o > 0; o >>= 1) ss += __shfl_down(ss, o);
  if (lane == 0) ws[wid] = ss;
  __syncthreads();
  if (threadIdx.x == 0) outv[b] = sqrtf(ws[0] + ws[1] + ws[2] + ws[3]);
}

// y = (S1/sqrt(s)) * (1 + ||S2||_F/sqrt(s)), upper-tri extract
__global__ __launch_bounds__(256)
void out2_k(const u16* __restrict__ Sh, const u16* __restrict__ Sl,
            const float* __restrict__ s, const float* __restrict__ attn,
            float* __restrict__ out)
{
  const int i = blockIdx.x, b = blockIdx.y, j = threadIdx.x;
  if (j < i) return;
  const float inv = rsqrtf(s[b]);
  const float nrm = fmaxf(attn[b] * inv, 1e-12f);
  const float scv = inv * (1.f + nrm);
  const long o = ((long)b * 256 + i) * 256 + j;
  const long off = (long)b * 32896 + (long)i * 256 - (long)i * (i - 1) / 2 + (j - i);
  out[off] = (bf2f(Sh[o]) + bf2f(Sl[o])) * scv;
}

extern "C" void kernel_launch(void* const* d_in, const int* in_sizes, int n_in,
                              void* d_out, int out_size, void* d_ws, size_t ws_size,
                              hipStream_t stream)
{
  const float* x     = (const float*)d_in[0];   // [32,2048,28,28]
  const float* w     = (const float*)d_in[1];   // [256,2048]
  const float* gamma = (const float*)d_in[2];
  const float* beta  = (const float*)d_in[3];
  float* out = (float*)d_out;

  // ---- workspace layout (bytes), total ~50.37 MB ----
  // pairs: 5 slots x 8 MB at [0, 41943040). Each slot: hi 4 MB then lo 4 MB.
  // cov fp32 [41943040, 50331648)  (wb bf16 aliases its first 1 MB pre-gram)
  // st floats at 50331648.
  // temporaries: z fp32 [0, 25690112) (dead before NS), zb [25690112, 39321600).
  const long PS = 4194304;   // ushorts per pair slot
  const long LO = 2097152;   // lo-plane offset (ushorts)
  u16* pairs = (u16*)d_ws;
  u16* An = pairs + 0 * PS;
  u16* Z1 = pairs + 1 * PS;
  u16* Z2 = pairs + 2 * PS;
  u16* U  = pairs + 3 * PS;
  u16* V  = pairs + 4 * PS;
  float* z   = (float*)d_ws;
  u16*   zb  = (u16*)((char*)d_ws + 25690112);
  float* cov = (float*)((char*)d_ws + 41943040);
  u16*   wb  = (u16*)((char*)d_ws + 41943040);
  float* st  = (float*)((char*)d_ws + 50331648);
  float* sum = st, *sumsq = st + 256, *scale = st + 512, *shift = st + 768;
  float* rs = st + 1024;       // 32*256
  float* sV = st + 9216;       // per-batch spectral scale
  float* attn = st + 9248;

  const dim3 blk(256);
  const dim3 grdG(2, 2, 32);

  auto G = [&](const u16* A_, const u16* B_, u16* C_, const u16* P_,
               float alpha, float b1, float diag) {
    if (P_)
      gemm2_k<true><<<grdG, blk, 0, stream>>>(A_, A_ + LO, B_, B_ + LO,
                                              C_, C_ + LO, P_, P_ + LO, alpha, b1, diag);
    else
      gemm2_k<false><<<grdG, blk, 0, stream>>>(A_, A_ + LO, B_, B_ + LO,
                                               C_, C_ + LO, (const u16*)nullptr,
                                               (const u16*)nullptr, alpha, 0.f, diag);
  };

  // 1) conv: cast W, then bf16 MFMA GEMM -> z fp32
  cast_w_k<<<dim3(2048), blk, 0, stream>>>(w, wb);
  conv_k<<<dim3(7, 1, 32), dim3(512), 0, stream>>>(wb, x, z);
  // 2) BN stats + params; 3) spatial rowsums; cast BN+ReLU(z) -> zb bf16
  bn_stats_k<<<dim3(256), blk, 0, stream>>>(z, sum, sumsq);
  bn_params_k<<<dim3(1), blk, 0, stream>>>(sum, sumsq, gamma, beta, scale, shift);
  rowsum_k<<<dim3(256, 32), dim3(64), 0, stream>>>(z, scale, shift, rs);
  bnrelu_cast_k<<<dim3(256, 32), blk, 0, stream>>>(z, scale, shift, zb);
  // 4) covariance (bf16 MFMA Gram) -> cov fp32 (overwrites wb: wb is dead)
  gram_k<<<grdG, blk, 0, stream>>>(zb, rs, cov);
  // 5) spectral scale s[b] = 1/(1.1*lambda_max); An = s*cov (split); Z = I
  power_k<<<dim3(32), blk, 0, stream>>>(cov, sV);
  init_ns_k<<<dim3(256, 32), blk, 0, stream>>>(cov, sV, An, An + LO, Z1, Z1 + LO);

  // 6) Z-only Newton-Schulz, 9 iters: U=An@Z; V=Z@U; Z' = 1.5Z - 0.5 V@Z
  for (int it = 0; it < 9; ++it) {
    u16* Zi = (it & 1) ? Z2 : Z1;
    u16* Zo = (it & 1) ? Z1 : Z2;
    G(An, Zi, U, nullptr, 1.f, 0.f, 0.f);
    G(Zi, U, V, nullptr, 1.f, 0.f, 0.f);
    G(V, Zi, Zo, Zi, -0.5f, 1.5f, 0.f);
  }
  // Zf = Z2.  S1 = An @ Zf = An^{1/2}  -> U
  G(An, Z2, U, nullptr, 1.f, 0.f, 0.f);

  // 7) expm(-cov): X = -cov/2 -> Z1; X2 -> V; PS deg-8 Horner; square
  x_init_k<<<dim3(256, 32), blk, 0, stream>>>(cov, Z1, Z1 + LO);
  G(Z1, Z1, V, nullptr, 1.f, 0.f, 0.f);                     // V  = X2
  h3_k<<<dim3(256, 32), blk, 0, stream>>>(V, V + LO, Z1, Z1 + LO, An, An + LO); // An = H3
  G(V, An, Z2, Z1, 1.f, 1.f / 120.f, 1.f / 24.f);           // Z2 = H2
  G(V, Z2, An, Z1, 1.f, 1.f / 6.f, 0.5f);                   // An = H1
  G(V, An, Z2, Z1, 1.f, 1.f, 1.f);                          // Z2 = H0 = e^X (deg 8)
  G(Z2, Z2, V, nullptr, 1.f, 0.f, 0.f);                     // V  = E = e^{-cov}

  // 8) S2 = S1@E -> An; nrm; epilogue
  G(U, V, An, nullptr, 1.f, 0.f, 0.f);
  frob2_k<<<dim3(32), blk, 0, stream>>>(An, An + LO, attn);
  out2_k<<<dim3(256, 32), blk, 0, stream>>>(U, U + LO, sV, attn, out);
}

// Round 4
// 818.507 us; speedup vs baseline: 3.2843x; 1.2993x over previous
//
#include <hip/hip_runtime.h>

// ============================================================================
// SEB_59201829208446 round 4:
//   conv1x1 (bf16 MFMA) -> fused BN(batch stats)+ReLU+cast -> Gram/cov (MFMA)
//   -> lambda_max via COALESCED power iteration (symmetric A: read columns)
//   -> coupled Newton-Schulz, 8 iters, s = 1.8/lambda: Y->An^{1/2}
//   -> expm(-cov) deg-8 Paterson-Stockmeyer, NO squaring (|cov|~0.9)
//   -> ||Y@E||_F folded into GEMM epilogue (atomic), epilogue scale, triu out.
// Split-bf16 GEMM everywhere (hi+lo planes, 3 MFMA products, fp32 accum).
// 26 launches (was 47); power_k coalesced (was 122 us uncoalesced).
// ============================================================================

typedef unsigned short u16;
typedef __attribute__((ext_vector_type(8))) short bf16x8;
typedef __attribute__((ext_vector_type(4))) float f32x4;

__device__ __forceinline__ u16 f2bf(float f) {
  unsigned u = __builtin_bit_cast(unsigned, f);
  u += 0x7FFFu + ((u >> 16) & 1u);
  return (u16)(u >> 16);
}
__device__ __forceinline__ float bf2f(u16 h) {
  unsigned u = ((unsigned)h) << 16;
  return __builtin_bit_cast(float, u);
}

// ---------------------------------------------------------------------------
// Core 128x128x256 split-bf16 tile compute (B must be symmetric).
// LDS XOR-swizzled chunk layout (2-way bank aliasing = free).
// ---------------------------------------------------------------------------
__device__ __forceinline__
void mm_core(const u16* __restrict__ Ah, const u16* __restrict__ Al,
             const u16* __restrict__ Bh, const u16* __restrict__ Bl,
             long boff, int row0, int col0,
             u16 (*lds)[128][8][8], f32x4 acc[4][4])
{
  const int tid = threadIdx.x;
  const int wave = tid >> 6, lane = tid & 63;
  const int wm = wave >> 1, wn = wave & 1;
  const int mL = lane & 15, q = lane >> 4;
  const u16* baseA[2] = {Ah + boff, Al + boff};
  const u16* baseB[2] = {Bh + boff, Bl + boff};

  for (int k0 = 0; k0 < 256; k0 += 64) {
    __syncthreads();
#pragma unroll
    for (int it = 0; it < 16; ++it) {
      const int t = it >> 2;                    // 0:Ah 1:Al 2:Bh 3:Bl
      const int r = ((it & 3) << 8) + tid;
      const int m = r >> 3, c = r & 7;
      const u16* src = (t < 2 ? baseA[t] : baseB[t - 2])
                     + (long)((t < 2 ? row0 : col0) + m) * 256 + k0 + c * 8;
      const uint4 v = *reinterpret_cast<const uint4*>(src);
      *reinterpret_cast<uint4*>(&lds[t][m][c ^ (m & 7)][0]) = v;
    }
    __syncthreads();
#pragma unroll
    for (int kk = 0; kk < 2; ++kk) {
      bf16x8 ah[4], al[4], bh[4], bl[4];
#pragma unroll
      for (int i = 0; i < 4; ++i) {
        const int ma = wm * 64 + i * 16 + mL;
        const int ca = (kk * 4 + q) ^ (ma & 7);
        ah[i] = *reinterpret_cast<const bf16x8*>(&lds[0][ma][ca][0]);
        al[i] = *reinterpret_cast<const bf16x8*>(&lds[1][ma][ca][0]);
        const int nb = wn * 64 + i * 16 + mL;
        const int cb = (kk * 4 + q) ^ (nb & 7);
        bh[i] = *reinterpret_cast<const bf16x8*>(&lds[2][nb][cb][0]);
        bl[i] = *reinterpret_cast<const bf16x8*>(&lds[3][nb][cb][0]);
      }
#pragma unroll
      for (int i = 0; i < 4; ++i)
#pragma unroll
        for (int j = 0; j < 4; ++j) {
          acc[i][j] = __builtin_amdgcn_mfma_f32_16x16x32_bf16(ah[i], bh[j], acc[i][j], 0, 0, 0);
          acc[i][j] = __builtin_amdgcn_mfma_f32_16x16x32_bf16(ah[i], bl[j], acc[i][j], 0, 0, 0);
          acc[i][j] = __builtin_amdgcn_mfma_f32_16x16x32_bf16(al[i], bh[j], acc[i][j], 0, 0, 0);
        }
    }
  }
}

// MODE 0: C = alpha*(A@B) + b1*covf + diag*I        (covf may be null)
// MODE 1: C = A@B;  D = C/40320 - covf/5040 + I/720 (dual out, for V/H3)
// MODE 2: no write; atomicAdd(attn2[z], ||A@B||_F^2 partial)
template<int MODE>
__global__ __launch_bounds__(256)
void gemm2_k(const u16* __restrict__ Ah, const u16* __restrict__ Al,
             const u16* __restrict__ Bh, const u16* __restrict__ Bl,
             u16* __restrict__ Ch, u16* __restrict__ Cl,
             u16* __restrict__ Dh, u16* __restrict__ Dl,
             const float* __restrict__ covf,
             float alpha, float b1, float diag, float* __restrict__ attn2)
{
  __shared__ u16 lds[4][128][8][8];
  const long boff = (long)blockIdx.z * 65536;
  const int row0 = blockIdx.y * 128, col0 = blockIdx.x * 128;
  const int wave = threadIdx.x >> 6, lane = threadIdx.x & 63;
  const int wm = wave >> 1, wn = wave & 1;
  const int mL = lane & 15, q = lane >> 4;

  f32x4 acc[4][4];
#pragma unroll
  for (int i = 0; i < 4; ++i)
#pragma unroll
    for (int j = 0; j < 4; ++j) acc[i][j] = {0.f, 0.f, 0.f, 0.f};

  mm_core(Ah, Al, Bh, Bl, boff, row0, col0, lds, acc);

  if (MODE == 2) {
    float ssum = 0.f;
#pragma unroll
    for (int i = 0; i < 4; ++i)
#pragma unroll
      for (int j = 0; j < 4; ++j)
#pragma unroll
        for (int rg = 0; rg < 4; ++rg) ssum = fmaf(acc[i][j][rg], acc[i][j][rg], ssum);
#pragma unroll
    for (int o = 32; o > 0; o >>= 1) ssum += __shfl_down(ssum, o);
    __syncthreads();
    float* red = (float*)&lds[0][0][0][0];
    if (lane == 0) red[wave] = ssum;
    __syncthreads();
    if (threadIdx.x == 0)
      atomicAdd(attn2 + blockIdx.z, red[0] + red[1] + red[2] + red[3]);
    return;
  }

#pragma unroll
  for (int i = 0; i < 4; ++i) {
    const int rbase = row0 + wm * 64 + i * 16 + q * 4;
#pragma unroll
    for (int j = 0; j < 4; ++j) {
      const int cc = col0 + wn * 64 + j * 16 + mL;
#pragma unroll
      for (int rg = 0; rg < 4; ++rg) {
        const int rr = rbase + rg;
        const long o = boff + (long)rr * 256 + cc;
        if (MODE == 0) {
          float v = alpha * acc[i][j][rg];
          if (covf) v = fmaf(b1, covf[o], v);
          if (rr == cc) v += diag;
          const u16 h = f2bf(v);
          Ch[o] = h; Cl[o] = f2bf(v - bf2f(h));
        } else { // MODE 1
          const float v = acc[i][j][rg];
          u16 h = f2bf(v);
          Ch[o] = h; Cl[o] = f2bf(v - bf2f(h));
          float hv = v * (1.f / 40320.f) - covf[o] * (1.f / 5040.f);
          if (rr == cc) hv += 1.f / 720.f;
          h = f2bf(hv);
          Dh[o] = h; Dl[o] = f2bf(hv - bf2f(h));
        }
      }
    }
  }
}

// Fused pair: z<32 -> C0 = A0@B0 ; z>=32 -> C1 = A1@B1 (both plain, alpha=1)
__global__ __launch_bounds__(256)
void gemm2_pair_k(const u16* __restrict__ A0, const u16* __restrict__ B0, u16* __restrict__ C0,
                  const u16* __restrict__ A1, const u16* __restrict__ B1, u16* __restrict__ C1,
                  long LO)
{
  __shared__ u16 lds[4][128][8][8];
  int z = blockIdx.z;
  const u16 *Ah, *Bh; u16* Chp;
  if (z < 32) { Ah = A0; Bh = B0; Chp = C0; }
  else { z -= 32; Ah = A1; Bh = B1; Chp = C1; }
  const long boff = (long)z * 65536;
  const int row0 = blockIdx.y * 128, col0 = blockIdx.x * 128;
  const int wave = threadIdx.x >> 6, lane = threadIdx.x & 63;
  const int wm = wave >> 1, wn = wave & 1;
  const int mL = lane & 15, q = lane >> 4;

  f32x4 acc[4][4];
#pragma unroll
  for (int i = 0; i < 4; ++i)
#pragma unroll
    for (int j = 0; j < 4; ++j) acc[i][j] = {0.f, 0.f, 0.f, 0.f};

  mm_core(Ah, Ah + LO, Bh, Bh + LO, boff, row0, col0, lds, acc);

#pragma unroll
  for (int i = 0; i < 4; ++i) {
    const int rbase = row0 + wm * 64 + i * 16 + q * 4;
#pragma unroll
    for (int j = 0; j < 4; ++j) {
      const int cc = col0 + wn * 64 + j * 16 + mL;
#pragma unroll
      for (int rg = 0; rg < 4; ++rg) {
        const long o = boff + (long)(rbase + rg) * 256 + cc;
        const float v = acc[i][j][rg];
        const u16 h = f2bf(v);
        Chp[o] = h; Chp[o + LO] = f2bf(v - bf2f(h));
      }
    }
  }
}

// ---------------------------------------------------------------------------
// conv1x1: z[b] = W(256x2048) @ x_b(2048x784), bf16 MFMA, fp32 out. (round 3)
// ---------------------------------------------------------------------------
__global__ __launch_bounds__(512)
void conv_k(const u16* __restrict__ wb, const float* __restrict__ x,
            float* __restrict__ z)
{
  __shared__ u16 ldsA[256][8][8];
  __shared__ u16 ldsB[128][8][8];
  const int tid = threadIdx.x;
  const int b = blockIdx.z;
  const int n0 = blockIdx.x * 128;
  const int wave = tid >> 6, lane = tid & 63;
  const int wm = wave >> 1, wn = wave & 1;
  const int mL = lane & 15, q = lane >> 4;
  const float* xb = x + (long)b * 2048 * 784;

  f32x4 acc[4][4];
#pragma unroll
  for (int i = 0; i < 4; ++i)
#pragma unroll
    for (int j = 0; j < 4; ++j) acc[i][j] = {0.f, 0.f, 0.f, 0.f};

  for (int k0 = 0; k0 < 2048; k0 += 64) {
    __syncthreads();
#pragma unroll
    for (int it = 0; it < 4; ++it) {
      const int g = it * 512 + tid;
      const int m = g >> 3, c = g & 7;
      const uint4 v = *reinterpret_cast<const uint4*>(wb + (long)m * 2048 + k0 + c * 8);
      *reinterpret_cast<uint4*>(&ldsA[m][c ^ (m & 7)][0]) = v;
    }
    {
      const int kg = tid >> 5, nc = tid & 31;
      const int kbase = kg * 4, nbase = nc * 4;
      float vv[4][4];
#pragma unroll
      for (int jk = 0; jk < 4; ++jk) {
        const int gk = k0 + kbase + jk;
        const int gn = n0 + nbase;
        float4 f = make_float4(0.f, 0.f, 0.f, 0.f);
        if (gn < 784) f = *reinterpret_cast<const float4*>(xb + (long)gk * 784 + gn);
        vv[jk][0] = f.x; vv[jk][1] = f.y; vv[jk][2] = f.z; vv[jk][3] = f.w;
      }
      const int c = kbase >> 3, ko = kbase & 7;
#pragma unroll
      for (int jn = 0; jn < 4; ++jn) {
        const int n = nbase + jn;
        ushort4 u;
        u.x = f2bf(vv[0][jn]); u.y = f2bf(vv[1][jn]);
        u.z = f2bf(vv[2][jn]); u.w = f2bf(vv[3][jn]);
        *reinterpret_cast<ushort4*>(&ldsB[n][c ^ (n & 7)][ko]) = u;
      }
    }
    __syncthreads();
#pragma unroll
    for (int kk = 0; kk < 2; ++kk) {
      bf16x8 af[4], bfv[4];
#pragma unroll
      for (int i = 0; i < 4; ++i) {
        const int ma = wm * 64 + i * 16 + mL;
        af[i] = *reinterpret_cast<const bf16x8*>(&ldsA[ma][(kk * 4 + q) ^ (ma & 7)][0]);
        const int nb = wn * 64 + i * 16 + mL;
        bfv[i] = *reinterpret_cast<const bf16x8*>(&ldsB[nb][(kk * 4 + q) ^ (nb & 7)][0]);
      }
#pragma unroll
      for (int i = 0; i < 4; ++i)
#pragma unroll
        for (int j = 0; j < 4; ++j)
          acc[i][j] = __builtin_amdgcn_mfma_f32_16x16x32_bf16(af[i], bfv[j], acc[i][j], 0, 0, 0);
    }
  }
#pragma unroll
  for (int i = 0; i < 4; ++i) {
    const int rbase = wm * 64 + i * 16 + q * 4;
#pragma unroll
    for (int j = 0; j < 4; ++j) {
      const int cc = n0 + wn * 64 + j * 16 + mL;
      if (cc >= 784) continue;
#pragma unroll
      for (int rg = 0; rg < 4; ++rg)
        z[((long)b * 256 + rbase + rg) * 784 + cc] = acc[i][j][rg];
    }
  }
}

// ---------------------------------------------------------------------------
// Gram: cov[b] = (1/784) zb@zb^T - mu mu^T.  zb bf16 [256][832] (padded).
// ---------------------------------------------------------------------------
__global__ __launch_bounds__(256)
void gram_k(const u16* __restrict__ zb, const float* __restrict__ rs,
            float* __restrict__ cov)
{
  __shared__ u16 lds[2][128][8][8];
  const int tid = threadIdx.x;
  const int b = blockIdx.z;
  const int col0 = blockIdx.x * 128, row0 = blockIdx.y * 128;
  const int wave = tid >> 6, lane = tid & 63;
  const int wm = wave >> 1, wn = wave & 1;
  const int mL = lane & 15, q = lane >> 4;
  const u16* zbb = zb + (long)b * 256 * 832;

  f32x4 acc[4][4];
#pragma unroll
  for (int i = 0; i < 4; ++i)
#pragma unroll
    for (int j = 0; j < 4; ++j) acc[i][j] = {0.f, 0.f, 0.f, 0.f};

  for (int k0 = 0; k0 < 832; k0 += 64) {
    __syncthreads();
#pragma unroll
    for (int it = 0; it < 8; ++it) {
      const int t = it >> 2;
      const int r = ((it & 3) << 8) + tid;
      const int m = r >> 3, c = r & 7;
      const int grow = (t == 0 ? row0 : col0) + m;
      const uint4 v = *reinterpret_cast<const uint4*>(zbb + (long)grow * 832 + k0 + c * 8);
      *reinterpret_cast<uint4*>(&lds[t][m][c ^ (m & 7)][0]) = v;
    }
    __syncthreads();
#pragma unroll
    for (int kk = 0; kk < 2; ++kk) {
      bf16x8 af[4], bfv[4];
#pragma unroll
      for (int i = 0; i < 4; ++i) {
        const int ma = wm * 64 + i * 16 + mL;
        af[i] = *reinterpret_cast<const bf16x8*>(&lds[0][ma][(kk * 4 + q) ^ (ma & 7)][0]);
        const int nb = wn * 64 + i * 16 + mL;
        bfv[i] = *reinterpret_cast<const bf16x8*>(&lds[1][nb][(kk * 4 + q) ^ (nb & 7)][0]);
      }
#pragma unroll
      for (int i = 0; i < 4; ++i)
#pragma unroll
        for (int j = 0; j < 4; ++j)
          acc[i][j] = __builtin_amdgcn_mfma_f32_16x16x32_bf16(af[i], bfv[j], acc[i][j], 0, 0, 0);
    }
  }
  const float inv_m = 1.f / 784.f;
#pragma unroll
  for (int i = 0; i < 4; ++i) {
    const int rr0 = row0 + wm * 64 + i * 16 + q * 4;
#pragma unroll
    for (int j = 0; j < 4; ++j) {
      const int cc = col0 + wn * 64 + j * 16 + mL;
      const float mu_c = rs[b * 256 + cc] * inv_m;
#pragma unroll
      for (int rg = 0; rg < 4; ++rg) {
        const int rr = rr0 + rg;
        const float mu_r = rs[b * 256 + rr] * inv_m;
        cov[((long)b * 256 + rr) * 256 + cc] = fmaf(acc[i][j][rg], inv_m, -mu_r * mu_c);
      }
    }
  }
}

// ---- fused BN stats + params + ReLU/cast + rowsums (one block per channel d)
__global__ __launch_bounds__(256)
void bn_fuse_k(const float* __restrict__ z, const float* __restrict__ gamma,
               const float* __restrict__ beta, u16* __restrict__ zb,
               float* __restrict__ rs)
{
  const int d = blockIdx.x, t = threadIdx.x;
  const int lane = t & 63, wid = t >> 6;
  __shared__ float ws[4], wq[4], bc[2];

  float s = 0.f, qq = 0.f;
  for (int b = 0; b < 32; ++b) {
    const float* p = z + ((long)b * 256 + d) * 784;
    for (int m = t; m < 784; m += 256) {
      const float v = p[m];
      s += v; qq = fmaf(v, v, qq);
    }
  }
#pragma unroll
  for (int o = 32; o > 0; o >>= 1) { s += __shfl_down(s, o); qq += __shfl_down(qq, o); }
  if (lane == 0) { ws[wid] = s; wq[wid] = qq; }
  __syncthreads();
  if (t == 0) {
    const float inv_n = 1.f / 25088.f;
    const float sum = ws[0] + ws[1] + ws[2] + ws[3];
    const float sq  = wq[0] + wq[1] + wq[2] + wq[3];
    const float mean = sum * inv_n;
    const float var  = sq * inv_n - mean * mean;
    const float sc = gamma[d] * rsqrtf(var + 1e-5f);
    bc[0] = sc; bc[1] = fmaf(-mean, sc, beta[d]);
  }
  __syncthreads();
  const float sc = bc[0], sh = bc[1];

  for (int b = 0; b < 32; ++b) {
    const float* p = z + ((long)b * 256 + d) * 784;
    u16* qp = zb + ((long)b * 256 + d) * 832;
    float rsum = 0.f;
    for (int m = t; m < 832; m += 256) {
      const float v = (m < 784) ? fmaxf(fmaf(p[m], sc, sh), 0.f) : 0.f;
      qp[m] = f2bf(v);
      rsum += v;
    }
#pragma unroll
    for (int o = 32; o > 0; o >>= 1) rsum += __shfl_down(rsum, o);
    if (lane == 0) ws[wid] = rsum;
    __syncthreads();
    if (t == 0) rs[b * 256 + d] = ws[0] + ws[1] + ws[2] + ws[3];
    __syncthreads();
  }
}

// ---- coalesced power iteration (A symmetric: u_i = sum_j A[j][i] v_j) ----
__global__ __launch_bounds__(256)
void power_k(const float* __restrict__ cov, float* __restrict__ s,
             float* __restrict__ attn2)
{
  const int b = blockIdx.x, i = threadIdx.x;
  const float* A = cov + (long)b * 65536;
  __shared__ float v[256];
  __shared__ float red[4];
  v[i] = 1.f;
  __syncthreads();
  float lam = 1.f;
  for (int it = 0; it < 10; ++it) {
    float u = 0.f;
#pragma unroll 8
    for (int j = 0; j < 256; ++j) u = fmaf(A[(long)j * 256 + i], v[j], u);
    float ss = u * u;
#pragma unroll
    for (int o = 32; o > 0; o >>= 1) ss += __shfl_down(ss, o);
    if ((i & 63) == 0) red[i >> 6] = ss;
    __syncthreads();
    lam = sqrtf(red[0] + red[1] + red[2] + red[3]);
    v[i] = u / lam;
    __syncthreads();
  }
  if (i == 0) { s[b] = 1.8f / lam; attn2[b] = 0.f; }
}

// ---- init: Y0 = split(s*cov); T0 = split(1.5I - 0.5*s*cov)  (Z0 = I) ------
__global__ __launch_bounds__(256)
void init_k(const float* __restrict__ cov, const float* __restrict__ s,
            u16* __restrict__ Yh, u16* __restrict__ Yl,
            u16* __restrict__ Th, u16* __restrict__ Tl)
{
  const int b = blockIdx.y, i = blockIdx.x, j = threadIdx.x;
  const long o = ((long)b * 256 + i) * 256 + j;
  const float a = cov[o] * s[b];
  u16 h = f2bf(a);
  Yh[o] = h; Yl[o] = f2bf(a - bf2f(h));
  float tv = -0.5f * a;
  if (i == j) tv += 1.5f;
  h = f2bf(tv);
  Th[o] = h; Tl[o] = f2bf(tv - bf2f(h));
}

// ---- C2 = split(cov)  (operand for V = cov^2 = X^2) -----------------------
__global__ __launch_bounds__(256)
void split_cov_k(const float* __restrict__ cov, u16* __restrict__ Ch, u16* __restrict__ Cl)
{
  const int b = blockIdx.y, i = blockIdx.x, j = threadIdx.x;
  const long o = ((long)b * 256 + i) * 256 + j;
  const float a = cov[o];
  const u16 h = f2bf(a);
  Ch[o] = h; Cl[o] = f2bf(a - bf2f(h));
}

// ---- epilogue: y = (Y/sqrt(s)) * (1 + ||S2||_F/sqrt(s)), triu extract -----
__global__ __launch_bounds__(256)
void out_k(const u16* __restrict__ Yh, const u16* __restrict__ Yl,
           const float* __restrict__ s, const float* __restrict__ attn2,
           float* __restrict__ out)
{
  const int i = blockIdx.x, b = blockIdx.y, j = threadIdx.x;
  if (j < i) return;
  const float inv = rsqrtf(s[b]);
  const float nrm = fmaxf(sqrtf(fmaxf(attn2[b], 0.f)) * inv, 1e-12f);
  const float scv = inv * (1.f + nrm);
  const long o = ((long)b * 256 + i) * 256 + j;
  const long off = (long)b * 32896 + (long)i * 256 - (long)i * (i - 1) / 2 + (j - i);
  out[off] = (bf2f(Yh[o]) + bf2f(Yl[o])) * scv;
}

__global__ __launch_bounds__(256)
void cast_w_k(const float* __restrict__ w, u16* __restrict__ wb)
{
  const int idx = blockIdx.x * 256 + threadIdx.x;
  wb[idx] = f2bf(w[idx]);
}

extern "C" void kernel_launch(void* const* d_in, const int* in_sizes, int n_in,
                              void* d_out, int out_size, void* d_ws, size_t ws_size,
                              hipStream_t stream)
{
  const float* x     = (const float*)d_in[0];   // [32,2048,28,28]
  const float* w     = (const float*)d_in[1];   // [256,2048]
  const float* gamma = (const float*)d_in[2];
  const float* beta  = (const float*)d_in[3];
  float* out = (float*)d_out;

  // ---- workspace: 5 split-pair slots (8.39 MB each) + cov fp32 + small ----
  const long PS = 4194304;  // u16 per slot (hi 2,097,152 then lo 2,097,152)
  const long LO = 2097152;
  u16* S[5];
  for (int k = 0; k < 5; ++k) S[k] = (u16*)d_ws + (long)k * PS;
  float* z   = (float*)d_ws;                         // [0, 25690112) B, pre-NS
  u16*   zb  = (u16*)((char*)d_ws + 25690112);       // 13.6 MB, pre-NS
  float* cov = (float*)((char*)d_ws + 41943040);     // 8.39 MB
  u16*   wb  = (u16*)((char*)d_ws + 41943040);       // 1 MB, dead before gram
  float* st  = (float*)((char*)d_ws + 50331648);
  float* sv = st, *attn2 = st + 32, *rs = st + 64;   // 32 + 32 + 8192 floats

  const dim3 blk(256);
  const dim3 gM(2, 2, 32);
  const dim3 gP(2, 2, 64);
  const dim3 gE(256, 32);

  auto G0 = [&](const u16* A_, const u16* B_, u16* C_, const float* Pf,
                float alpha, float b1, float diag) {
    gemm2_k<0><<<gM, blk, 0, stream>>>(A_, A_ + LO, B_, B_ + LO, C_, C_ + LO,
                                       (u16*)nullptr, (u16*)nullptr, Pf,
                                       alpha, b1, diag, (float*)nullptr);
  };

  // 1) conv -> z fp32
  cast_w_k<<<dim3(2048), blk, 0, stream>>>(w, wb);
  conv_k<<<dim3(7, 1, 32), dim3(512), 0, stream>>>(wb, x, z);
  // 2) fused BN stats+params+ReLU+cast+rowsums
  bn_fuse_k<<<dim3(256), blk, 0, stream>>>(z, gamma, beta, zb, rs);
  // 3) covariance
  gram_k<<<gM, blk, 0, stream>>>(zb, rs, cov);
  // 4) lambda_max (coalesced); s = 1.8/lam; zero attn2
  power_k<<<dim3(32), blk, 0, stream>>>(cov, sv, attn2);
  // 5) NS init: Y0 -> S0, T0 -> S1 (Z0 = I => Z1 = T0)
  init_k<<<gE, blk, 0, stream>>>(cov, sv, S[0], S[0] + LO, S[1], S[1] + LO);
  // it0: Y1 = Y0@T0 -> S2
  G0(S[0], S[1], S[2], nullptr, 1.f, 0.f, 0.f);

  // 6) coupled NS iters 1..7: T = 1.5I - 0.5*Z@Y; (Y,Z) <- (Y@T, T@Z)
  int iY = 2, iZ = 1, fa = 0, fb = 3, fc = 4;
  for (int it = 1; it <= 7; ++it) {
    const int iT = fa;
    G0(S[iZ], S[iY], S[iT], nullptr, -0.5f, 0.f, 1.5f);
    if (it < 7) {
      gemm2_pair_k<<<gP, blk, 0, stream>>>(S[iY], S[iT], S[fb],
                                           S[iT], S[iZ], S[fc], LO);
      const int nY = fb, nZ = fc;
      fa = iY; fb = iZ; fc = iT;
      iY = nY; iZ = nZ;
    } else {            // last iter: Z not needed
      G0(S[iY], S[iT], S[fb], nullptr, 1.f, 0.f, 0.f);
      iY = fb;
    }
  }
  // Y_final = S[iY] = An^{1/2};  free slots: the other four.
  int fr[4], nf = 0;
  for (int k = 0; k < 5; ++k) if (k != iY) fr[nf++] = k;
  u16* C2 = S[fr[0]]; u16* V = S[fr[1]]; u16* Ha = S[fr[2]]; u16* Hb = S[fr[3]];

  // 7) expm(-cov), deg-8 PS, no squaring. X = -cov (P-terms read cov fp32).
  split_cov_k<<<gE, blk, 0, stream>>>(cov, C2, C2 + LO);
  // V = cov^2 (= X^2); dual-out: Ha = H3 = V/40320 - cov/5040 + I/720
  gemm2_k<1><<<gM, blk, 0, stream>>>(C2, C2 + LO, C2, C2 + LO, V, V + LO,
                                     Ha, Ha + LO, cov, 1.f, 0.f, 0.f, (float*)nullptr);
  G0(V, Ha, Hb, cov, 1.f, -1.f / 120.f, 1.f / 24.f);  // Hb = H2
  G0(V, Hb, Ha, cov, 1.f, -1.f / 6.f,   0.5f);        // Ha = H1
  G0(V, Ha, Hb, cov, 1.f, -1.f,         1.f);         // Hb = H0 = e^{-cov}

  // 8) ||Y@E||_F^2 -> attn2 (atomic, no C write); epilogue
  gemm2_k<2><<<gM, blk, 0, stream>>>(S[iY], S[iY] + LO, Hb, Hb + LO,
                                     (u16*)nullptr, (u16*)nullptr,
                                     (u16*)nullptr, (u16*)nullptr,
                                     (const float*)nullptr, 1.f, 0.f, 0.f, attn2);
  out_k<<<gE, blk, 0, stream>>>(S[iY], S[iY] + LO, sv, attn2, out);
}